// Round 2
// baseline (763.583 us; speedup 1.0000x reference)
//
#include <hip/hip_runtime.h>
#include <hip/hip_cooperative_groups.h>

namespace cg = cooperative_groups;

#define N_NODES 100000
#define N_EDGES 600000
// N_EDGES/4 = 150000 exact; N_NODES/2 = 50000 exact

// One cooperative kernel, 7 phases separated by grid.sync():
//  P1: z[n] = dot(x[n,:], W);  dis[n] = 1.0   (half-wave per node, float4)
//  P2: dis[col[e]] += 1                        (degree incl. self loop)
//  P3: dis = rsqrt(deg); y = dis*z; t = y      (t init = self-loop term)
//  P4: t[col] += y[row]                        (hop 1)
//  P5: v = dis^2 * t; y = v; t = v             (finish hop1 scale + pre-scale hop2)
//  P6: t[col] += y[row]                        (hop 2)
//  P7: out = dis * t + b
__global__ void __launch_bounds__(256, 4) sgc_fused(
    const float* __restrict__ x,
    const int*   __restrict__ row,
    const int*   __restrict__ col,
    const float* __restrict__ W,
    const float* __restrict__ b,
    float* __restrict__ dis,   // deg -> dis
    float* __restrict__ z,     // z0 -> y0 -> y1
    float* __restrict__ t,     // scatter accumulator
    float* __restrict__ out)
{
    cg::grid_group grid = cg::this_grid();
    const int tid  = blockIdx.x * blockDim.x + threadIdx.x;
    const int nth  = gridDim.x * blockDim.x;
    const int lane = threadIdx.x & 63;
    const int wid  = tid >> 6;
    const int nwav = nth >> 6;
    const int half = lane >> 5;      // which 32-lane group
    const int hl   = lane & 31;      // lane within half-wave

    // ---- P1: projection (2 nodes per wave per iter; 32 lanes x float4 = 128 floats)
    {
        float4 wv = ((const float4*)W)[hl];
        for (int p = wid; p < N_NODES / 2; p += nwav) {
            int n = 2 * p + half;
            float4 xv = ((const float4*)(x + (size_t)n * 128))[hl];
            float s = xv.x * wv.x + xv.y * wv.y + xv.z * wv.z + xv.w * wv.w;
            s += __shfl_xor(s, 16, 32);
            s += __shfl_xor(s,  8, 32);
            s += __shfl_xor(s,  4, 32);
            s += __shfl_xor(s,  2, 32);
            s += __shfl_xor(s,  1, 32);
            if (hl == 0) { z[n] = s; dis[n] = 1.0f; }
        }
    }
    grid.sync();

    // ---- P2: degree atomics
    for (int i = tid; i < N_EDGES / 4; i += nth) {
        int4 c = ((const int4*)col)[i];
        atomicAdd(&dis[c.x], 1.0f);
        atomicAdd(&dis[c.y], 1.0f);
        atomicAdd(&dis[c.z], 1.0f);
        atomicAdd(&dis[c.w], 1.0f);
    }
    grid.sync();

    // ---- P3: normalize + init accumulator with self-loop term
    for (int n = tid; n < N_NODES; n += nth) {
        float d = rsqrtf(dis[n]);      // deg >= 1 always
        dis[n] = d;
        float y = d * z[n];
        z[n] = y;
        t[n] = y;
    }
    grid.sync();

    // ---- P4: hop-1 scatter
    for (int i = tid; i < N_EDGES / 4; i += nth) {
        int4 r = ((const int4*)row)[i];
        int4 c = ((const int4*)col)[i];
        float y0 = z[r.x], y1 = z[r.y], y2 = z[r.z], y3 = z[r.w];
        atomicAdd(&t[c.x], y0);
        atomicAdd(&t[c.y], y1);
        atomicAdd(&t[c.z], y2);
        atomicAdd(&t[c.w], y3);
    }
    grid.sync();

    // ---- P5: finish hop-1 scale (dis) + pre-scale for hop 2 (dis) => dis^2
    for (int n = tid; n < N_NODES; n += nth) {
        float d = dis[n];
        float v = d * d * t[n];
        z[n] = v;
        t[n] = v;
    }
    grid.sync();

    // ---- P6: hop-2 scatter
    for (int i = tid; i < N_EDGES / 4; i += nth) {
        int4 r = ((const int4*)row)[i];
        int4 c = ((const int4*)col)[i];
        float y0 = z[r.x], y1 = z[r.y], y2 = z[r.z], y3 = z[r.w];
        atomicAdd(&t[c.x], y0);
        atomicAdd(&t[c.y], y1);
        atomicAdd(&t[c.z], y2);
        atomicAdd(&t[c.w], y3);
    }
    grid.sync();

    // ---- P7: final scale + bias
    {
        float bb = b[0];
        for (int n = tid; n < N_NODES; n += nth)
            out[n] = dis[n] * t[n] + bb;
    }
}

extern "C" void kernel_launch(void* const* d_in, const int* in_sizes, int n_in,
                              void* d_out, int out_size, void* d_ws, size_t ws_size,
                              hipStream_t stream) {
    const float* x  = (const float*)d_in[0];
    const int*   ei = (const int*)  d_in[1];   // [2,E] int32 on device
    const float* W  = (const float*)d_in[2];
    const float* b  = (const float*)d_in[3];
    float* out = (float*)d_out;

    float* dis = (float*)d_ws;
    float* z   = dis + N_NODES;
    float* t   = z + N_NODES;

    const int* row = ei;
    const int* col = ei + N_EDGES;

    // 1024 blocks x 256 threads = 4 blocks/CU (16 waves/CU) — safely co-resident
    // for cooperative launch (cap is 8 blocks/CU at this register/LDS footprint).
    dim3 grid(1024), block(256);
    void* args[] = { (void*)&x, (void*)&row, (void*)&col, (void*)&W, (void*)&b,
                     (void*)&dis, (void*)&z, (void*)&t, (void*)&out };
    hipLaunchCooperativeKernel((void*)sgc_fused, grid, block, args, 0, stream);
}

// Round 3
// 193.766 us; speedup vs baseline: 3.9407x; 3.9407x over previous
//
#include <hip/hip_runtime.h>

#define N_NODES 100000
#define N_EDGES 600000
#define D_FEAT  128
// N_EDGES/4 = 150000 exact; N_NODES/2 = 50000 exact

// Math (S = D^-1/2 (A+I) D^-1/2, z = x.W^T, out = S^2 z + b), with
// y = dis*z, P = (dis^2, dis^2*y), edge-only accumulators t1e/t2e:
//   t1e[c] = sum_e y[row_e]                          (K3)
//   t2e[c] = sum_e (P[r].x*t1e[r] + P[r].y)          (K4)
//   out[n] = dis[n]*(t2e[n] + P[n].x*t1e[n] + P[n].y) + b   (K5)

// K1: z[n] = dot(x[n,:], W)  (half-wave per node, float4 coalesced)
//     deg[c] += 1 per edge   (deg zero-memset; independent of projection)
__global__ void k1_proj_deg(const float* __restrict__ x,
                            const float* __restrict__ W,
                            const int*   __restrict__ col,
                            float* __restrict__ z,
                            float* __restrict__ deg) {
    const int tid  = blockIdx.x * blockDim.x + threadIdx.x;
    const int nth  = gridDim.x * blockDim.x;
    const int wid  = tid >> 6;
    const int nwav = nth >> 6;
    const int lane = threadIdx.x & 63;
    const int half = lane >> 5;
    const int hl   = lane & 31;

    float4 wv = ((const float4*)W)[hl];
    for (int p = wid; p < N_NODES / 2; p += nwav) {
        int n = 2 * p + half;
        float4 xv = ((const float4*)(x + (size_t)n * D_FEAT))[hl];
        float s = xv.x * wv.x + xv.y * wv.y + xv.z * wv.z + xv.w * wv.w;
        s += __shfl_xor(s, 16, 32);
        s += __shfl_xor(s,  8, 32);
        s += __shfl_xor(s,  4, 32);
        s += __shfl_xor(s,  2, 32);
        s += __shfl_xor(s,  1, 32);
        if (hl == 0) z[n] = s;
    }
    // degree (edge-only; self loop added in K2)
    for (int i = tid; i < N_EDGES / 4; i += nth) {
        int4 c = ((const int4*)col)[i];
        atomicAdd(&deg[c.x], 1.0f);
        atomicAdd(&deg[c.y], 1.0f);
        atomicAdd(&deg[c.z], 1.0f);
        atomicAdd(&deg[c.w], 1.0f);
    }
}

// K2: dis = rsqrt(deg+1); y = dis*z; P = (dis^2, dis^2*y)
__global__ void k2_norm(const float* __restrict__ deg,
                        const float* __restrict__ z,
                        float* __restrict__ dis,
                        float* __restrict__ y,
                        float2* __restrict__ P) {
    int n = blockIdx.x * blockDim.x + threadIdx.x;
    if (n >= N_NODES) return;
    float d = rsqrtf(deg[n] + 1.0f);
    dis[n] = d;
    float yv = d * z[n];
    y[n] = yv;
    float d2 = d * d;
    P[n] = make_float2(d2, d2 * yv);
}

// K3: t1e[col] += y[row]
__global__ void k3_hop1(const int* __restrict__ row,
                        const int* __restrict__ col,
                        const float* __restrict__ y,
                        float* __restrict__ t1e) {
    int i = blockIdx.x * blockDim.x + threadIdx.x;
    if (i >= N_EDGES / 4) return;
    int4 r = ((const int4*)row)[i];
    int4 c = ((const int4*)col)[i];
    float y0 = y[r.x], y1 = y[r.y], y2 = y[r.z], y3 = y[r.w];
    atomicAdd(&t1e[c.x], y0);
    atomicAdd(&t1e[c.y], y1);
    atomicAdd(&t1e[c.z], y2);
    atomicAdd(&t1e[c.w], y3);
}

// K4: t2e[col] += P[row].x * t1e[row] + P[row].y
__global__ void k4_hop2(const int* __restrict__ row,
                        const int* __restrict__ col,
                        const float2* __restrict__ P,
                        const float* __restrict__ t1e,
                        float* __restrict__ t2e) {
    int i = blockIdx.x * blockDim.x + threadIdx.x;
    if (i >= N_EDGES / 4) return;
    int4 r = ((const int4*)row)[i];
    int4 c = ((const int4*)col)[i];
    float2 p0 = P[r.x], p1 = P[r.y], p2 = P[r.z], p3 = P[r.w];
    float v0 = p0.x * t1e[r.x] + p0.y;
    float v1 = p1.x * t1e[r.y] + p1.y;
    float v2 = p2.x * t1e[r.z] + p2.y;
    float v3 = p3.x * t1e[r.w] + p3.y;
    atomicAdd(&t2e[c.x], v0);
    atomicAdd(&t2e[c.y], v1);
    atomicAdd(&t2e[c.z], v2);
    atomicAdd(&t2e[c.w], v3);
}

// K5: out[n] = dis[n]*(t2e[n] + P[n].x*t1e[n] + P[n].y) + b
__global__ void k5_final(const float* __restrict__ dis,
                         const float* __restrict__ t1e,
                         const float* __restrict__ t2e,
                         const float2* __restrict__ P,
                         const float* __restrict__ b,
                         float* __restrict__ out) {
    int n = blockIdx.x * blockDim.x + threadIdx.x;
    if (n >= N_NODES) return;
    float2 p = P[n];
    out[n] = dis[n] * (t2e[n] + p.x * t1e[n] + p.y) + b[0];
}

extern "C" void kernel_launch(void* const* d_in, const int* in_sizes, int n_in,
                              void* d_out, int out_size, void* d_ws, size_t ws_size,
                              hipStream_t stream) {
    const float* x  = (const float*)d_in[0];
    const int*   ei = (const int*)  d_in[1];   // [2,E] as int32; row=ei[0:E], col=ei[E:2E]
    const float* W  = (const float*)d_in[2];
    const float* b  = (const float*)d_in[3];
    float* out = (float*)d_out;

    // ws layout: [deg | t1e | t2e | z | dis | y | P(float2)]
    float*  deg = (float*)d_ws;
    float*  t1e = deg + N_NODES;
    float*  t2e = t1e + N_NODES;
    float*  z   = t2e + N_NODES;
    float*  dis = z   + N_NODES;
    float*  y   = dis + N_NODES;
    float2* P   = (float2*)(y + N_NODES);

    const int* row = ei;
    const int* col = ei + N_EDGES;

    const int B = 256;
    const int grid_node = (N_NODES + B - 1) / B;       // 391
    const int grid_edge = (N_EDGES / 4 + B - 1) / B;   // 586

    // zero the three atomic accumulators (deg,t1e,t2e contiguous)
    hipMemsetAsync(deg, 0, 3 * N_NODES * sizeof(float), stream);

    k1_proj_deg<<<2048, B, 0, stream>>>(x, W, col, z, deg);
    k2_norm    <<<grid_node, B, 0, stream>>>(deg, z, dis, y, P);
    k3_hop1    <<<grid_edge, B, 0, stream>>>(row, col, y, t1e);
    k4_hop2    <<<grid_edge, B, 0, stream>>>(row, col, P, t1e, t2e);
    k5_final   <<<grid_node, B, 0, stream>>>(dis, t1e, t2e, P, b, out);
}